// Round 4
// baseline (2944.900 us; speedup 1.0000x reference)
//
#include <hip/hip_runtime.h>
#include <hip/hip_bf16.h>

#define N_MOL 128
#define STRESS_FLOATS (N_MOL * 9)   // 1152

// ---------------------------------------------------------------------------
// Kernel 1: zero the whole output buffer (forces region + stress region).
// d_out is poisoned 0xAA once and never re-poisoned between replays, and we
// accumulate with atomics, so we must re-zero every call.
// ---------------------------------------------------------------------------
__global__ void zero_out_kernel(float4* __restrict__ out, int n4) {
    int stride = gridDim.x * blockDim.x;
    for (int i = blockIdx.x * blockDim.x + threadIdx.x; i < n4; i += stride) {
        out[i] = make_float4(0.f, 0.f, 0.f, 0.f);
    }
}

// ---------------------------------------------------------------------------
// Kernel 2: edge scatter.
//  forces[idx_i] += dEdRij ; forces[idx_j] -= dEdRij   (global HW atomics)
//  stress[mol(idx_i)][a][b] += Rij[a]*dEdRij[b]        (LDS accum -> global)
// ---------------------------------------------------------------------------
__global__ void __launch_bounds__(256)
edge_kernel(const float* __restrict__ dEdRij,
            const float* __restrict__ Rij,
            const int*   __restrict__ idx_i,
            const int*   __restrict__ idx_j,
            const int*   __restrict__ idx_m,
            float* __restrict__ forces,       // [N*3] at d_out
            float* __restrict__ stress_acc,   // [1152] at d_out + N*3
            int E)
{
    __shared__ float smem[STRESS_FLOATS];
    for (int t = threadIdx.x; t < STRESS_FLOATS; t += blockDim.x)
        smem[t] = 0.f;
    __syncthreads();

    const int stride = gridDim.x * blockDim.x;
    for (int e = blockIdx.x * blockDim.x + threadIdx.x; e < E; e += stride) {
        const int i = idx_i[e];
        const int j = idx_j[e];

        const float dx = dEdRij[3 * e + 0];
        const float dy = dEdRij[3 * e + 1];
        const float dz = dEdRij[3 * e + 2];
        const float rx = Rij[3 * e + 0];
        const float ry = Rij[3 * e + 1];
        const float rz = Rij[3 * e + 2];

        // Forces: += into i, -= into j (fire-and-forget HW f32 atomics)
        unsafeAtomicAdd(&forces[3 * i + 0],  dx);
        unsafeAtomicAdd(&forces[3 * i + 1],  dy);
        unsafeAtomicAdd(&forces[3 * i + 2],  dz);
        unsafeAtomicAdd(&forces[3 * j + 0], -dx);
        unsafeAtomicAdd(&forces[3 * j + 1], -dy);
        unsafeAtomicAdd(&forces[3 * j + 2], -dz);

        // Stress: outer(Rij, dEdRij) accumulated per-molecule in LDS.
        const int m = idx_m[i];
        float* s = &smem[m * 9];
        atomicAdd(&s[0], rx * dx);   // ds_add_f32 — native LDS f32 atomic
        atomicAdd(&s[1], rx * dy);
        atomicAdd(&s[2], rx * dz);
        atomicAdd(&s[3], ry * dx);
        atomicAdd(&s[4], ry * dy);
        atomicAdd(&s[5], ry * dz);
        atomicAdd(&s[6], rz * dx);
        atomicAdd(&s[7], rz * dy);
        atomicAdd(&s[8], rz * dz);
    }

    __syncthreads();
    for (int t = threadIdx.x; t < STRESS_FLOATS; t += blockDim.x) {
        unsafeAtomicAdd(&stress_acc[t], smem[t]);
    }
}

// ---------------------------------------------------------------------------
// Kernel 3: finalize stress in place: divide by cell volume per molecule.
//  volume[m] = cell[m,0] . (cell[m,1] x cell[m,2])
// ---------------------------------------------------------------------------
__global__ void finalize_stress_kernel(const float* __restrict__ cell,
                                       float* __restrict__ stress_acc)
{
    int t = blockIdx.x * blockDim.x + threadIdx.x;
    if (t >= STRESS_FLOATS) return;
    const int m = t / 9;
    const float* c = &cell[m * 9];
    const float a0 = c[0], a1 = c[1], a2 = c[2];
    const float b0 = c[3], b1 = c[4], b2 = c[5];
    const float c0 = c[6], c1 = c[7], c2 = c[8];
    // cross(b, c)
    const float x0 = b1 * c2 - b2 * c1;
    const float x1 = b2 * c0 - b0 * c2;
    const float x2 = b0 * c1 - b1 * c0;
    const float vol = a0 * x0 + a1 * x1 + a2 * x2;
    stress_acc[t] = stress_acc[t] / vol;
}

extern "C" void kernel_launch(void* const* d_in, const int* in_sizes, int n_in,
                              void* d_out, int out_size, void* d_ws, size_t ws_size,
                              hipStream_t stream)
{
    const float* dEdRij = (const float*)d_in[0];
    const float* Rij    = (const float*)d_in[1];
    const float* R      = (const float*)d_in[2];  (void)R;
    const float* cell   = (const float*)d_in[3];
    const int*   idx_i  = (const int*)d_in[4];
    const int*   idx_j  = (const int*)d_in[5];
    const int*   idx_m  = (const int*)d_in[6];

    const int E = in_sizes[0] / 3;   // 10,000,000
    const int N = in_sizes[2] / 3;   // 200,000

    float* out        = (float*)d_out;
    float* forces     = out;                 // N*3 floats
    float* stress_acc = out + (size_t)N * 3; // 1152 floats

    // out_size = N*3 + 1152 = 601152, divisible by 4
    const int n4 = out_size / 4;
    zero_out_kernel<<<(n4 + 255) / 256, 256, 0, stream>>>((float4*)out, n4);

    const int blocks = 2048;  // 8 blocks/CU, grid-stride over edges
    edge_kernel<<<blocks, 256, 0, stream>>>(dEdRij, Rij, idx_i, idx_j, idx_m,
                                            forces, stress_acc, E);

    finalize_stress_kernel<<<(STRESS_FLOATS + 255) / 256, 256, 0, stream>>>(
        cell, stress_acc);
}

// Round 6
// 2762.813 us; speedup vs baseline: 1.0659x; 1.0659x over previous
//
#include <hip/hip_runtime.h>
#include <hip/hip_bf16.h>

#define N_MOL 128
#define STRESS_FLOATS (N_MOL * 9)   // 1152
#define EDGE_BLOCKS 2048
#define BLK 256

// ---------------------------------------------------------------------------
// zero the f64 force accumulator in ws (atomics accumulate -> re-zero per call)
// ---------------------------------------------------------------------------
__global__ void zero_f64_kernel(double* __restrict__ p, int n) {
    int i = blockIdx.x * blockDim.x + threadIdx.x;
    if (i < n) p[i] = 0.0;
}

// ---------------------------------------------------------------------------
// Edge kernel:
//  forces: 3 f64 atomics/edge-endpoint pair-halved: global_atomic_add_f64
//          (halves coherent-atomic transaction count vs 6x f32)
//  stress: LDS accumulate -> non-atomic per-block partial [EDGE_BLOCKS][1152]
// ---------------------------------------------------------------------------
__global__ void __launch_bounds__(256)
edge_kernel_f64(const float* __restrict__ dEdRij,
                const float* __restrict__ Rij,
                const int*   __restrict__ idx_i,
                const int*   __restrict__ idx_j,
                const int*   __restrict__ idx_m,
                double* __restrict__ facc,    // [N][3] f64
                float*  __restrict__ spart,   // [EDGE_BLOCKS][1152]
                int E)
{
    __shared__ float smem[STRESS_FLOATS];
    for (int t = threadIdx.x; t < STRESS_FLOATS; t += blockDim.x)
        smem[t] = 0.f;
    __syncthreads();

    const int stride = gridDim.x * blockDim.x;
    for (int e = blockIdx.x * blockDim.x + threadIdx.x; e < E; e += stride) {
        const int i = idx_i[e];
        const int j = idx_j[e];

        const float dx = dEdRij[3 * e + 0];
        const float dy = dEdRij[3 * e + 1];
        const float dz = dEdRij[3 * e + 2];
        const float rx = Rij[3 * e + 0];
        const float ry = Rij[3 * e + 1];
        const float rz = Rij[3 * e + 2];

        // Forces: 3+3 f64 HW atomics (global_atomic_add_f64, fire-and-forget)
        double* fi = facc + 3 * (size_t)i;
        unsafeAtomicAdd(fi + 0, (double) dx);
        unsafeAtomicAdd(fi + 1, (double) dy);
        unsafeAtomicAdd(fi + 2, (double) dz);
        double* fj = facc + 3 * (size_t)j;
        unsafeAtomicAdd(fj + 0, (double)-dx);
        unsafeAtomicAdd(fj + 1, (double)-dy);
        unsafeAtomicAdd(fj + 2, (double)-dz);

        // Stress: outer(Rij, dEdRij) per-molecule in LDS (ds_add_f32)
        const int m = idx_m[i];
        float* s = &smem[m * 9];
        atomicAdd(&s[0], rx * dx);
        atomicAdd(&s[1], rx * dy);
        atomicAdd(&s[2], rx * dz);
        atomicAdd(&s[3], ry * dx);
        atomicAdd(&s[4], ry * dy);
        atomicAdd(&s[5], ry * dz);
        atomicAdd(&s[6], rz * dx);
        atomicAdd(&s[7], rz * dy);
        atomicAdd(&s[8], rz * dz);
    }

    __syncthreads();
    // non-atomic per-block stress partial flush
    float* sp = spart + (size_t)blockIdx.x * STRESS_FLOATS;
    for (int t = threadIdx.x; t < STRESS_FLOATS; t += blockDim.x)
        sp[t] = smem[t];
}

// ---------------------------------------------------------------------------
// forces f64 -> f32 into d_out (full overwrite; no d_out zeroing needed)
// ---------------------------------------------------------------------------
__global__ void reduce_forces_kernel(const double* __restrict__ facc,
                                     float* __restrict__ forces, int n3)
{
    int t = blockIdx.x * blockDim.x + threadIdx.x;
    if (t < n3) forces[t] = (float)facc[t];
}

// ---------------------------------------------------------------------------
// stress partials [EDGE_BLOCKS][1152] -> d_out [1152], divided by cell volume
// ---------------------------------------------------------------------------
__global__ void reduce_stress_kernel(const float* __restrict__ spart,
                                     const float* __restrict__ cell,
                                     float* __restrict__ out_stress,
                                     int nblocks)
{
    int t = blockIdx.x * blockDim.x + threadIdx.x;
    if (t >= STRESS_FLOATS) return;
    float acc = 0.f;
    #pragma unroll 8
    for (int b = 0; b < nblocks; ++b)
        acc += spart[(size_t)b * STRESS_FLOATS + t];
    const int m = t / 9;
    const float* c = &cell[m * 9];
    const float a0 = c[0], a1 = c[1], a2 = c[2];
    const float b0 = c[3], b1 = c[4], b2 = c[5];
    const float c0 = c[6], c1 = c[7], c2 = c[8];
    const float x0 = b1 * c2 - b2 * c1;
    const float x1 = b2 * c0 - b0 * c2;
    const float x2 = b0 * c1 - b1 * c0;
    const float vol = a0 * x0 + a1 * x1 + a2 * x2;
    out_stress[t] = acc / vol;
}

// ===========================================================================
// Fallback path (ws too small): round-4 direct-atomic version (known passing)
// ===========================================================================
__global__ void zero_out_kernel(float4* __restrict__ out, int n4) {
    int stride = gridDim.x * blockDim.x;
    for (int i = blockIdx.x * blockDim.x + threadIdx.x; i < n4; i += stride)
        out[i] = make_float4(0.f, 0.f, 0.f, 0.f);
}

__global__ void __launch_bounds__(256)
edge_kernel_direct(const float* __restrict__ dEdRij,
                   const float* __restrict__ Rij,
                   const int*   __restrict__ idx_i,
                   const int*   __restrict__ idx_j,
                   const int*   __restrict__ idx_m,
                   float* __restrict__ forces,
                   float* __restrict__ stress_acc,
                   int E)
{
    __shared__ float smem[STRESS_FLOATS];
    for (int t = threadIdx.x; t < STRESS_FLOATS; t += blockDim.x) smem[t] = 0.f;
    __syncthreads();
    const int stride = gridDim.x * blockDim.x;
    for (int e = blockIdx.x * blockDim.x + threadIdx.x; e < E; e += stride) {
        const int i = idx_i[e], j = idx_j[e];
        const float dx = dEdRij[3*e+0], dy = dEdRij[3*e+1], dz = dEdRij[3*e+2];
        const float rx = Rij[3*e+0],    ry = Rij[3*e+1],    rz = Rij[3*e+2];
        unsafeAtomicAdd(&forces[3*i+0],  dx);
        unsafeAtomicAdd(&forces[3*i+1],  dy);
        unsafeAtomicAdd(&forces[3*i+2],  dz);
        unsafeAtomicAdd(&forces[3*j+0], -dx);
        unsafeAtomicAdd(&forces[3*j+1], -dy);
        unsafeAtomicAdd(&forces[3*j+2], -dz);
        const int m = idx_m[i];
        float* s = &smem[m * 9];
        atomicAdd(&s[0], rx*dx); atomicAdd(&s[1], rx*dy); atomicAdd(&s[2], rx*dz);
        atomicAdd(&s[3], ry*dx); atomicAdd(&s[4], ry*dy); atomicAdd(&s[5], ry*dz);
        atomicAdd(&s[6], rz*dx); atomicAdd(&s[7], rz*dy); atomicAdd(&s[8], rz*dz);
    }
    __syncthreads();
    for (int t = threadIdx.x; t < STRESS_FLOATS; t += blockDim.x)
        unsafeAtomicAdd(&stress_acc[t], smem[t]);
}

__global__ void finalize_stress_kernel(const float* __restrict__ cell,
                                       float* __restrict__ stress_acc)
{
    int t = blockIdx.x * blockDim.x + threadIdx.x;
    if (t >= STRESS_FLOATS) return;
    const int m = t / 9;
    const float* c = &cell[m * 9];
    const float a0 = c[0], a1 = c[1], a2 = c[2];
    const float b0 = c[3], b1 = c[4], b2 = c[5];
    const float c0 = c[6], c1 = c[7], c2 = c[8];
    const float x0 = b1*c2 - b2*c1, x1 = b2*c0 - b0*c2, x2 = b0*c1 - b1*c0;
    const float vol = a0*x0 + a1*x1 + a2*x2;
    stress_acc[t] = stress_acc[t] / vol;
}

// ===========================================================================
extern "C" void kernel_launch(void* const* d_in, const int* in_sizes, int n_in,
                              void* d_out, int out_size, void* d_ws, size_t ws_size,
                              hipStream_t stream)
{
    const float* dEdRij = (const float*)d_in[0];
    const float* Rij    = (const float*)d_in[1];
    const float* R      = (const float*)d_in[2];  (void)R;
    const float* cell   = (const float*)d_in[3];
    const int*   idx_i  = (const int*)d_in[4];
    const int*   idx_j  = (const int*)d_in[5];
    const int*   idx_m  = (const int*)d_in[6];

    const int E = in_sizes[0] / 3;   // 10,000,000
    const int N = in_sizes[2] / 3;   // 200,000

    float* out        = (float*)d_out;
    float* forces     = out;
    float* stress_out = out + (size_t)N * 3;

    const size_t facc_doubles = (size_t)N * 3;                        // 4.8 MB
    const size_t spart_floats = (size_t)EDGE_BLOCKS * STRESS_FLOATS;  // 9.4 MB
    const size_t need_bytes = facc_doubles * sizeof(double)
                            + spart_floats * sizeof(float);

    if (ws_size >= need_bytes) {
        double* facc  = (double*)d_ws;
        float*  spart = (float*)(facc + facc_doubles);

        const int n3 = (int)facc_doubles;  // 600,000
        zero_f64_kernel<<<(n3 + BLK - 1) / BLK, BLK, 0, stream>>>(facc, n3);

        edge_kernel_f64<<<EDGE_BLOCKS, BLK, 0, stream>>>(
            dEdRij, Rij, idx_i, idx_j, idx_m, facc, spart, E);

        reduce_forces_kernel<<<(n3 + BLK - 1) / BLK, BLK, 0, stream>>>(
            facc, forces, n3);

        reduce_stress_kernel<<<(STRESS_FLOATS + BLK - 1) / BLK, BLK, 0, stream>>>(
            spart, cell, stress_out, EDGE_BLOCKS);
    } else {
        // fallback: direct atomics into d_out (round-4 measured behavior)
        const int n4 = out_size / 4;
        zero_out_kernel<<<(n4 + BLK - 1) / BLK, BLK, 0, stream>>>((float4*)out, n4);
        edge_kernel_direct<<<EDGE_BLOCKS, BLK, 0, stream>>>(
            dEdRij, Rij, idx_i, idx_j, idx_m, forces, stress_out, E);
        finalize_stress_kernel<<<(STRESS_FLOATS + BLK - 1) / BLK, BLK, 0, stream>>>(
            cell, stress_out);
    }
}